// Round 4
// baseline (154.325 us; speedup 1.0000x reference)
//
#include <hip/hip_runtime.h>

typedef __attribute__((ext_vector_type(8))) short bf16x8;
typedef __attribute__((ext_vector_type(4))) float f32x4;
typedef __attribute__((ext_vector_type(16))) float f32x16;

__device__ __forceinline__ unsigned short f2bf(float f) {  // RNE
    union { float f; unsigned u; } v; v.f = f;
    return (unsigned short)((v.u + 0x7FFFu + ((v.u >> 16) & 1u)) >> 16);
}

__device__ __forceinline__ float fexp2(float v) {
#if __has_builtin(__builtin_amdgcn_exp2f)
    return __builtin_amdgcn_exp2f(v);
#else
    float r; asm("v_exp_f32 %0, %1" : "=v"(r) : "v"(v)); return r;
#endif
}
// pack two f32 -> two bf16 (RNE) in one instr (T12 primitive)
__device__ __forceinline__ unsigned cvt_pk_bf16(float lo, float hi) {
    unsigned r;
    asm("v_cvt_pk_bf16_f32 %0, %1, %2" : "=v"(r) : "v"(lo), "v"(hi));
    return r;
}

__device__ __forceinline__ void async16(unsigned short* lds, const unsigned short* gsrc) {
    __builtin_amdgcn_global_load_lds(
        (const __attribute__((address_space(1))) void*)gsrc,
        (__attribute__((address_space(3))) void*)lds, 16, 0, 0);
}

// ---------------- Kernel 0: weight transpose + bf16 cast (swizzled) ------
// kf rows (n<32) pre-scaled by log2(e): softmax exp(s) == exp2(s_scaled),
// so k_attn uses raw v_exp_f32 with no per-element multiply.
__global__ __launch_bounds__(256) void k_wt(const float* __restrict__ kf,
                                            const float* __restrict__ kg,
                                            const float* __restrict__ kh,
                                            unsigned short* __restrict__ wt) {
    int n = blockIdx.x, t = threadIdx.x;
    const float* src; int stride, col;
    if (n < 32)      { src = kf; stride = 32;  col = n; }
    else if (n < 64) { src = kg; stride = 32;  col = n - 32; }
    else             { src = kh; stride = 256; col = n - 64; }
    float v = src[t * stride + col];
    if (n < 32) v *= 1.44269504088896341f;     // log2(e)
    wt[n * 256 + (((t >> 3) ^ (n & 7)) << 3) + (t & 7)] = f2bf(v);
}

// ---------------- Kernel 1: projections (unchanged, verified) ------------
__global__ __launch_bounds__(512) void k_proj(const float* __restrict__ x,
                                              const unsigned short* __restrict__ wt,
                                              unsigned short* __restrict__ f,
                                              unsigned short* __restrict__ g,
                                              unsigned short* __restrict__ hT) {
    __shared__ unsigned short xs[16384];      // 64 x 256 bf16, swizzled  32 KB
    __shared__ unsigned short ws[2][16384];   // W tile dbuf              64 KB
    int t = threadIdx.x, rb = blockIdx.x;
    int w = t >> 6, lane = t & 63, q = lane >> 4, n15 = lane & 15;
    int b = rb >> 6, nbase = (rb & 63) * 64;

#pragma unroll
    for (int i = 0; i < 8; ++i) {
        int lin = i * 512 + t, row = lin >> 6, c4 = lin & 63;
        float4 v = *(const float4*)&x[(rb * 64 + row) * 256 + c4 * 4];
        ushort4 o; o.x = f2bf(v.x); o.y = f2bf(v.y); o.z = f2bf(v.z); o.w = f2bf(v.w);
        *(ushort4*)&xs[row * 256 + (((c4 >> 1) ^ (row & 7)) << 3) + ((c4 & 1) << 2)] = o;
    }
#pragma unroll
    for (int j = 0; j < 4; ++j)
        async16(&ws[0][(j * 512 + w * 64) * 8], wt + (j * 512 + t) * 8);

    for (int ct = 0; ct < 5; ++ct) {
        int cur = ct & 1, nxt = cur ^ 1;
        __syncthreads();
        if (ct < 4) {
            const unsigned short* wsrc = wt + (ct + 1) * 16384;
#pragma unroll
            for (int j = 0; j < 4; ++j)
                async16(&ws[nxt][(j * 512 + w * 64) * 8], wsrc + (j * 512 + t) * 8);
        }
        const unsigned short* wcur = ws[cur];
        f32x4 acc[2];
        acc[0] = (f32x4){0.f, 0.f, 0.f, 0.f};
        acc[1] = (f32x4){0.f, 0.f, 0.f, 0.f};

        if (ct == 0) {                         // f,g : D[m=row][n=col]
            int rg = w & 3, cg = w >> 2;
#pragma unroll
            for (int kk = 0; kk < 8; ++kk) {
                bf16x8 a = *(const bf16x8*)&xs[(rg * 16 + n15) * 256
                                + ((((kk << 2) + q) ^ (n15 & 7)) << 3)];
#pragma unroll
                for (int nt = 0; nt < 2; ++nt) {
                    bf16x8 bw = *(const bf16x8*)&wcur[(cg * 32 + nt * 16 + n15) * 256
                                    + ((((kk << 2) + q) ^ (n15 & 7)) << 3)];
                    acc[nt] = __builtin_amdgcn_mfma_f32_16x16x32_bf16(a, bw, acc[nt], 0, 0, 0);
                }
            }
#pragma unroll
            for (int nt = 0; nt < 2; ++nt)
#pragma unroll
                for (int r = 0; r < 4; ++r) {
                    int grow = rb * 64 + rg * 16 + q * 4 + r;
                    int col = cg * 32 + nt * 16 + n15;
                    unsigned short v = f2bf(acc[nt][r]);
                    if (col < 32) f[grow * 32 + col] = v;
                    else          g[grow * 32 + (col - 32)] = v;
                }
        } else {                               // h : D[m=ch][n=row] (swapped)
            int cg = w & 3, rg = w >> 2;
#pragma unroll
            for (int kk = 0; kk < 8; ++kk) {
                bf16x8 a = *(const bf16x8*)&wcur[(cg * 16 + n15) * 256
                                + ((((kk << 2) + q) ^ (n15 & 7)) << 3)];
#pragma unroll
                for (int nt = 0; nt < 2; ++nt) {
                    bf16x8 bx = *(const bf16x8*)&xs[(rg * 32 + nt * 16 + n15) * 256
                                    + ((((kk << 2) + q) ^ (n15 & 7)) << 3)];
                    acc[nt] = __builtin_amdgcn_mfma_f32_16x16x32_bf16(a, bx, acc[nt], 0, 0, 0);
                }
            }
#pragma unroll
            for (int nt = 0; nt < 2; ++nt)
#pragma unroll
                for (int r = 0; r < 4; ++r) {
                    int ch = (ct - 1) * 64 + cg * 16 + q * 4 + r;
                    int nloc = nbase + rg * 32 + nt * 16 + n15;
                    hT[b * 1048576 + ch * 4096 + nloc] = f2bf(acc[nt][r]);
                }
        }
    }
}

// ---------------- Kernel 2: fused flash attention + residual -------------
// R3 structure (73.3 us verified: grid 512, 512 thr, key-split S waves,
// exp2 path, cvt_pk packing, setprio) with ONE change:
//   PV phase hoists all 12 LDS fragments (bH/aP0/aP1, statically indexed
//   register arrays) BEFORE the MFMA cluster. R3's VGPR_Count=52 proved the
//   compiler serialized read->lgkmcnt->MFMA pairs (no regs to prefetch),
//   exposing ~120cy LDS latency repeatedly. Now: 12 back-to-back
//   ds_read_b128, latency overlapped, then 8 MFMAs stream.
__global__ __launch_bounds__(512, 4) void k_attn(const float* __restrict__ x,
                                                 const unsigned short* __restrict__ f,
                                                 const unsigned short* __restrict__ g,
                                                 const unsigned short* __restrict__ hT,
                                                 const float* __restrict__ gamma_p,
                                                 float* __restrict__ out) {
    __shared__ unsigned short hs[2][8192];     // 128 ch x 64 keys, swizzled 32 KB
    __shared__ unsigned short pls[2][4096];    // P dbuf: 64 rows x 64 keys  16 KB
    __shared__ float lpart[4][64];             // per-S-wave key-partial row sums
    __shared__ __align__(16) float lrec[64];   // per-row 1/l
    int t = threadIdx.x, bx = blockIdx.x;
    int b = (bx >> 1) & 3;                     // one batch per XCD-pair
    int ch2 = (bx >> 3) & 1;                   // channel half (128 ch)
    int qt = ((bx & 1) << 5) | (bx >> 4);      // 64 Q-tiles of 64 rows
    int qbase = qt * 64;
    int chbase = ch2 * 128;
    int w = t >> 6, l = t & 63;
    int hi = l >> 5, l31 = l & 31;             // 32x32 roles (PV)
    int q = l >> 4, n15 = l & 15;              // 16x16 roles (S)
    int cb = w & 3;                            // PV ch-block (w>=4)
    const bool is_s = (w < 4);

    // ---- S-wave state: key-split. Wave w owns keys [kt*64+w*16, +16). ----
    bf16x8 aFB[4];
    const unsigned short* gW = g + (b * 4096 + w * 16 + n15) * 32 + q * 8;  // +kt*2048
    if (is_s) {
#pragma unroll
        for (int nt = 0; nt < 4; ++nt)
            aFB[nt] = *(const bf16x8*)&f[(b * 4096 + qbase + nt * 16 + n15) * 32 + q * 8];
    }
    bf16x8 aG, aGn;
    f32x4 lac = (f32x4){0.f, 0.f, 0.f, 0.f};   // l partials per nt (row group)
    const f32x4 zero4 = (f32x4){0.f, 0.f, 0.f, 0.f};

    // hs staging: chunks c = j*512 + t; local ch = j*64+(t>>3);
    // phys seg t&7 holds logical seg (t&7)^(ch&7).
    const unsigned short* hsrc = hT + b * 1048576 + (chbase + (t >> 3)) * 4096
                               + (((t & 7) ^ ((t >> 3) & 7)) << 3);

    // S-step for tile in aG -> pls[buf].
    // D[m=key w*16+4q+r][n=qrow nt*16+n15]; key-quad kq = 4w+q.
    auto s_tile = [&](int buf) {
        f32x4 sa[4];
#pragma unroll
        for (int nt = 0; nt < 4; ++nt)
            sa[nt] = __builtin_amdgcn_mfma_f32_16x16x32_bf16(aG, aFB[nt], zero4, 0, 0, 0);
        int kq = w * 4 + q;
#pragma unroll
        for (int nt = 0; nt < 4; ++nt) {
#pragma unroll
            for (int r = 0; r < 4; ++r) {
                sa[nt][r] = fexp2(sa[nt][r]);  // f pre-scaled by log2(e)
                lac[nt] += sa[nt][r];
            }
            unsigned p0 = cvt_pk_bf16(sa[nt][0], sa[nt][1]);
            unsigned p1 = cvt_pk_bf16(sa[nt][2], sa[nt][3]);
            int row = nt * 16 + n15;
            // phys = row*128B + ((kq>>1)^(row&7))*16B + (kq&1)*8B
            unsigned* dst = (unsigned*)&pls[buf][row * 64]
                          + (((kq >> 1) ^ (n15 & 7)) << 2) + ((kq & 1) << 1);
            dst[0] = p0; dst[1] = p1;
        }
    };

    f32x16 o0, o1;
#pragma unroll
    for (int i = 0; i < 16; ++i) { o0[i] = 0.f; o1[i] = 0.f; }

    // ---- prologue: hs(0) prefetch; S(0) -> pls[0]; aG <- tile 1 ----
    async16(&hs[0][w * 512], hsrc);
    async16(&hs[0][4096 + w * 512], hsrc + 64 * 4096);
    if (is_s) {
        aG  = *(const bf16x8*)&gW[0];
        aGn = *(const bf16x8*)&gW[2048];
        s_tile(0);
        aG = aGn;
    }
    __syncthreads();   // publishes pls[0]; drains hs[0]

    for (int kt = 0; kt < 64; ++kt) {
        int cur = kt & 1, nxt = cur ^ 1;

        if (kt + 1 < 64) {                     // hs(kt+1) flies over this phase
            const unsigned short* hp = hsrc + (kt + 1) * 64;
            async16(&hs[nxt][w * 512], hp);
            async16(&hs[nxt][4096 + w * 512], hp + 64 * 4096);
        }

        if (is_s) {
            if (kt + 1 < 64) {
                int ktn = (kt + 2 < 64) ? kt + 2 : 63;
                aGn = *(const bf16x8*)&gW[ktn * 2048];   // flies during s_tile
                s_tile(nxt);                             // S(kt+1) from aG
                aG = aGn;
            }
        } else {
            // ---- O += P(kt).H(kt) : hoist 12 frags, then 8 MFMAs ----
            const unsigned short* hcur = &hs[cur][0];
            const unsigned short* pcur = &pls[cur][0];
            bf16x8 bH[4], aP0[4], aP1[4];
#pragma unroll
            for (int ks = 0; ks < 4; ++ks) {
                int seg = (((2 * ks + hi) ^ (l31 & 7)) << 3);
                bH[ks]  = *(const bf16x8*)&hcur[(cb * 32 + l31) * 64 + seg];
                aP0[ks] = *(const bf16x8*)&pcur[l31 * 64 + seg];
                aP1[ks] = *(const bf16x8*)&pcur[(32 + l31) * 64 + seg];
            }
            __builtin_amdgcn_s_setprio(1);
#pragma unroll
            for (int ks = 0; ks < 4; ++ks) {
                o0 = __builtin_amdgcn_mfma_f32_32x32x16_bf16(aP0[ks], bH[ks], o0, 0, 0, 0);
                o1 = __builtin_amdgcn_mfma_f32_32x32x16_bf16(aP1[ks], bH[ks], o1, 0, 0, 0);
            }
            __builtin_amdgcn_s_setprio(0);
        }

        __syncthreads();   // publish pls[nxt]; drain hs[nxt] DMA
    }

    // ---- epilogue: l reduce (4 key-partials per row), O/l, residual ----
    if (is_s) {
#pragma unroll
        for (int nt = 0; nt < 4; ++nt) {
            float ps = lac[nt];
            ps += __shfl_xor(ps, 16);
            ps += __shfl_xor(ps, 32);
            if (q == 0) lpart[w][nt * 16 + n15] = ps;
        }
    }
    __syncthreads();
    if (t < 64) lrec[t] = 1.0f / (lpart[0][t] + lpart[1][t] + lpart[2][t] + lpart[3][t]);
    __syncthreads();
    if (!is_s) {
        float gam = *gamma_p;
        int ch = chbase + cb * 32 + l31;
#pragma unroll
        for (int qq = 0; qq < 4; ++qq) {
            int r0 = 8 * qq + 4 * hi;
            f32x4 ri0 = *(const f32x4*)&lrec[r0];
            f32x4 ri1 = *(const f32x4*)&lrec[32 + r0];
#pragma unroll
            for (int j = 0; j < 4; ++j) {
                int idx0 = (b * 4096 + qbase + r0 + j) * 256 + ch;
                int idx1 = idx0 + 32 * 256;
                out[idx0] = x[idx0] + gam * (o0[4 * qq + j] * ri0[j]);
                out[idx1] = x[idx1] + gam * (o1[4 * qq + j] * ri1[j]);
            }
        }
    }
}

// ---------------- launch ------------------------------------------------
extern "C" void kernel_launch(void* const* d_in, const int* in_sizes, int n_in,
                              void* d_out, int out_size, void* d_ws, size_t ws_size,
                              hipStream_t stream) {
    const float* x  = (const float*)d_in[0];
    const float* kf = (const float*)d_in[1];
    const float* kg = (const float*)d_in[2];
    const float* kh = (const float*)d_in[3];
    const float* gm = (const float*)d_in[4];
    float* out = (float*)d_out;

    char* ws = (char*)d_ws;
    unsigned short* wt = (unsigned short*)(ws);             // 320*256*2   = 163840 B
    unsigned short* fb = (unsigned short*)(ws + 163840);    // 16384*32*2  = 1 MiB
    unsigned short* gb = (unsigned short*)(ws + 1212416);   // 16384*32*2  = 1 MiB
    unsigned short* hT = (unsigned short*)(ws + 2260992);   // 4*256*4096*2= 8 MiB

    hipLaunchKernelGGL(k_wt,   dim3(320), dim3(256), 0, stream, kf, kg, kh, wt);
    hipLaunchKernelGGL(k_proj, dim3(256), dim3(512), 0, stream, x, wt, fb, gb, hT);
    hipLaunchKernelGGL(k_attn, dim3(512), dim3(512), 0, stream, x, fb, gb, hT, gm, out);
}

// Round 5
// 144.755 us; speedup vs baseline: 1.0661x; 1.0661x over previous
//
#include <hip/hip_runtime.h>

typedef __attribute__((ext_vector_type(8))) short bf16x8;
typedef __attribute__((ext_vector_type(4))) float f32x4;
typedef __attribute__((ext_vector_type(16))) float f32x16;

__device__ __forceinline__ unsigned short f2bf(float f) {  // RNE
    union { float f; unsigned u; } v; v.f = f;
    return (unsigned short)((v.u + 0x7FFFu + ((v.u >> 16) & 1u)) >> 16);
}

__device__ __forceinline__ float fexp2(float v) {
#if __has_builtin(__builtin_amdgcn_exp2f)
    return __builtin_amdgcn_exp2f(v);
#else
    float r; asm("v_exp_f32 %0, %1" : "=v"(r) : "v"(v)); return r;
#endif
}
// pack two f32 -> two bf16 (RNE) in one instr (T12 primitive)
__device__ __forceinline__ unsigned cvt_pk_bf16(float lo, float hi) {
    unsigned r;
    asm("v_cvt_pk_bf16_f32 %0, %1, %2" : "=v"(r) : "v"(lo), "v"(hi));
    return r;
}

__device__ __forceinline__ void async16(unsigned short* lds, const unsigned short* gsrc) {
    __builtin_amdgcn_global_load_lds(
        (const __attribute__((address_space(1))) void*)gsrc,
        (__attribute__((address_space(3))) void*)lds, 16, 0, 0);
}

// ---------------- Kernel 0: weight transpose + bf16 cast (swizzled) ------
// kf rows (n<32) pre-scaled by log2(e): softmax exp(s) == exp2(s_scaled),
// so k_attn uses raw v_exp_f32 with no per-element multiply.
__global__ __launch_bounds__(256) void k_wt(const float* __restrict__ kf,
                                            const float* __restrict__ kg,
                                            const float* __restrict__ kh,
                                            unsigned short* __restrict__ wt) {
    int n = blockIdx.x, t = threadIdx.x;
    const float* src; int stride, col;
    if (n < 32)      { src = kf; stride = 32;  col = n; }
    else if (n < 64) { src = kg; stride = 32;  col = n - 32; }
    else             { src = kh; stride = 256; col = n - 64; }
    float v = src[t * stride + col];
    if (n < 32) v *= 1.44269504088896341f;     // log2(e)
    wt[n * 256 + (((t >> 3) ^ (n & 7)) << 3) + (t & 7)] = f2bf(v);
}

// ---------------- Kernel 1: projections (unchanged, verified) ------------
__global__ __launch_bounds__(512) void k_proj(const float* __restrict__ x,
                                              const unsigned short* __restrict__ wt,
                                              unsigned short* __restrict__ f,
                                              unsigned short* __restrict__ g,
                                              unsigned short* __restrict__ hT) {
    __shared__ unsigned short xs[16384];      // 64 x 256 bf16, swizzled  32 KB
    __shared__ unsigned short ws[2][16384];   // W tile dbuf              64 KB
    int t = threadIdx.x, rb = blockIdx.x;
    int w = t >> 6, lane = t & 63, q = lane >> 4, n15 = lane & 15;
    int b = rb >> 6, nbase = (rb & 63) * 64;

#pragma unroll
    for (int i = 0; i < 8; ++i) {
        int lin = i * 512 + t, row = lin >> 6, c4 = lin & 63;
        float4 v = *(const float4*)&x[(rb * 64 + row) * 256 + c4 * 4];
        ushort4 o; o.x = f2bf(v.x); o.y = f2bf(v.y); o.z = f2bf(v.z); o.w = f2bf(v.w);
        *(ushort4*)&xs[row * 256 + (((c4 >> 1) ^ (row & 7)) << 3) + ((c4 & 1) << 2)] = o;
    }
#pragma unroll
    for (int j = 0; j < 4; ++j)
        async16(&ws[0][(j * 512 + w * 64) * 8], wt + (j * 512 + t) * 8);

    for (int ct = 0; ct < 5; ++ct) {
        int cur = ct & 1, nxt = cur ^ 1;
        __syncthreads();
        if (ct < 4) {
            const unsigned short* wsrc = wt + (ct + 1) * 16384;
#pragma unroll
            for (int j = 0; j < 4; ++j)
                async16(&ws[nxt][(j * 512 + w * 64) * 8], wsrc + (j * 512 + t) * 8);
        }
        const unsigned short* wcur = ws[cur];
        f32x4 acc[2];
        acc[0] = (f32x4){0.f, 0.f, 0.f, 0.f};
        acc[1] = (f32x4){0.f, 0.f, 0.f, 0.f};

        if (ct == 0) {                         // f,g : D[m=row][n=col]
            int rg = w & 3, cg = w >> 2;
#pragma unroll
            for (int kk = 0; kk < 8; ++kk) {
                bf16x8 a = *(const bf16x8*)&xs[(rg * 16 + n15) * 256
                                + ((((kk << 2) + q) ^ (n15 & 7)) << 3)];
#pragma unroll
                for (int nt = 0; nt < 2; ++nt) {
                    bf16x8 bw = *(const bf16x8*)&wcur[(cg * 32 + nt * 16 + n15) * 256
                                    + ((((kk << 2) + q) ^ (n15 & 7)) << 3)];
                    acc[nt] = __builtin_amdgcn_mfma_f32_16x16x32_bf16(a, bw, acc[nt], 0, 0, 0);
                }
            }
#pragma unroll
            for (int nt = 0; nt < 2; ++nt)
#pragma unroll
                for (int r = 0; r < 4; ++r) {
                    int grow = rb * 64 + rg * 16 + q * 4 + r;
                    int col = cg * 32 + nt * 16 + n15;
                    unsigned short v = f2bf(acc[nt][r]);
                    if (col < 32) f[grow * 32 + col] = v;
                    else          g[grow * 32 + (col - 32)] = v;
                }
        } else {                               // h : D[m=ch][n=row] (swapped)
            int cg = w & 3, rg = w >> 2;
#pragma unroll
            for (int kk = 0; kk < 8; ++kk) {
                bf16x8 a = *(const bf16x8*)&wcur[(cg * 16 + n15) * 256
                                + ((((kk << 2) + q) ^ (n15 & 7)) << 3)];
#pragma unroll
                for (int nt = 0; nt < 2; ++nt) {
                    bf16x8 bx = *(const bf16x8*)&xs[(rg * 32 + nt * 16 + n15) * 256
                                    + ((((kk << 2) + q) ^ (n15 & 7)) << 3)];
                    acc[nt] = __builtin_amdgcn_mfma_f32_16x16x32_bf16(a, bx, acc[nt], 0, 0, 0);
                }
            }
#pragma unroll
            for (int nt = 0; nt < 2; ++nt)
#pragma unroll
                for (int r = 0; r < 4; ++r) {
                    int ch = (ct - 1) * 64 + cg * 16 + q * 4 + r;
                    int nloc = nbase + rg * 32 + nt * 16 + n15;
                    hT[b * 1048576 + ch * 4096 + nloc] = f2bf(acc[nt][r]);
                }
        }
    }
}

// ---------------- Kernel 2: fused flash attention + residual -------------
// R3 structure (73.3 us verified) with ONE structural change (T3/T4):
//   hs triple-buffered; in-loop __syncthreads (vmcnt(0) drain) replaced by
//   counted s_waitcnt + raw s_barrier. DMA(kt+2) issued at iter kt; barrier
//   only requires DMA(kt+1) retired -> each DMA has ~2 phases to land
//   instead of <1. In-flight accounting (in-order vmcnt retirement, m135):
//     steady state: S waves vmcnt(3) [2 DMA + aGn] + lgkmcnt(0) [pls writes]
//                   PV waves vmcnt(2) [2 DMA]
//     tail (no DMA issued this iter): S vmcnt(1), PV vmcnt(0).
//   sched_barrier(0) fences pin the asm (rule #18).
// PV fragment reads back to R3 inline form (R4 hoist regressed: forced
// lgkmcnt(0) before the MFMA cluster; compiler's counted interleave wins).
__global__ __launch_bounds__(512, 4) void k_attn(const float* __restrict__ x,
                                                 const unsigned short* __restrict__ f,
                                                 const unsigned short* __restrict__ g,
                                                 const unsigned short* __restrict__ hT,
                                                 const float* __restrict__ gamma_p,
                                                 float* __restrict__ out) {
    __shared__ unsigned short hs[3][8192];     // 128 ch x 64 keys, 3-buf  48 KB
    __shared__ unsigned short pls[2][4096];    // P dbuf: 64 rows x 64 keys 16 KB
    __shared__ float lpart[4][64];             // per-S-wave key-partial row sums
    __shared__ __align__(16) float lrec[64];   // per-row 1/l
    int t = threadIdx.x, bx = blockIdx.x;
    int b = (bx >> 1) & 3;                     // one batch per XCD-pair
    int ch2 = (bx >> 3) & 1;                   // channel half (128 ch)
    int qt = ((bx & 1) << 5) | (bx >> 4);      // 64 Q-tiles of 64 rows
    int qbase = qt * 64;
    int chbase = ch2 * 128;
    int w = t >> 6, l = t & 63;
    int hi = l >> 5, l31 = l & 31;             // 32x32 roles (PV)
    int q = l >> 4, n15 = l & 15;              // 16x16 roles (S)
    int cb = w & 3;                            // PV ch-block (w>=4)
    const bool is_s = (w < 4);

    // ---- S-wave state: key-split. Wave w owns keys [kt*64+w*16, +16). ----
    bf16x8 aFB[4];
    const unsigned short* gW = g + (b * 4096 + w * 16 + n15) * 32 + q * 8;  // +kt*2048
    if (is_s) {
#pragma unroll
        for (int nt = 0; nt < 4; ++nt)
            aFB[nt] = *(const bf16x8*)&f[(b * 4096 + qbase + nt * 16 + n15) * 32 + q * 8];
    }
    bf16x8 aG, aGn;
    f32x4 lac = (f32x4){0.f, 0.f, 0.f, 0.f};   // l partials per nt (row group)
    const f32x4 zero4 = (f32x4){0.f, 0.f, 0.f, 0.f};

    // hs staging: chunks c = j*512 + t; local ch = j*64+(t>>3);
    // phys seg t&7 holds logical seg (t&7)^(ch&7).
    const unsigned short* hsrc = hT + b * 1048576 + (chbase + (t >> 3)) * 4096
                               + (((t & 7) ^ ((t >> 3) & 7)) << 3);

    // S-step for tile in aG -> pls[buf].
    // D[m=key w*16+4q+r][n=qrow nt*16+n15]; key-quad kq = 4w+q.
    auto s_tile = [&](int buf) {
        f32x4 sa[4];
#pragma unroll
        for (int nt = 0; nt < 4; ++nt)
            sa[nt] = __builtin_amdgcn_mfma_f32_16x16x32_bf16(aG, aFB[nt], zero4, 0, 0, 0);
        int kq = w * 4 + q;
#pragma unroll
        for (int nt = 0; nt < 4; ++nt) {
#pragma unroll
            for (int r = 0; r < 4; ++r) {
                sa[nt][r] = fexp2(sa[nt][r]);  // f pre-scaled by log2(e)
                lac[nt] += sa[nt][r];
            }
            unsigned p0 = cvt_pk_bf16(sa[nt][0], sa[nt][1]);
            unsigned p1 = cvt_pk_bf16(sa[nt][2], sa[nt][3]);
            int row = nt * 16 + n15;
            // phys = row*128B + ((kq>>1)^(row&7))*16B + (kq&1)*8B
            unsigned* dst = (unsigned*)&pls[buf][row * 64]
                          + (((kq >> 1) ^ (n15 & 7)) << 2) + ((kq & 1) << 1);
            dst[0] = p0; dst[1] = p1;
        }
    };

    f32x16 o0, o1;
#pragma unroll
    for (int i = 0; i < 16; ++i) { o0[i] = 0.f; o1[i] = 0.f; }

    // ---- prologue: DMA hs(0),hs(1); S(0) -> pls[0]; aG <- tile 1 ----
    async16(&hs[0][w * 512], hsrc);
    async16(&hs[0][4096 + w * 512], hsrc + 64 * 4096);
    async16(&hs[1][w * 512], hsrc + 64);
    async16(&hs[1][4096 + w * 512], hsrc + 64 * 4096 + 64);
    if (is_s) {
        aG  = *(const bf16x8*)&gW[0];
        aGn = *(const bf16x8*)&gW[2048];
        s_tile(0);
        aG = aGn;
        __builtin_amdgcn_sched_barrier(0);
        asm volatile("s_waitcnt vmcnt(3) lgkmcnt(0)" ::: "memory");
    } else {
        __builtin_amdgcn_sched_barrier(0);
        asm volatile("s_waitcnt vmcnt(2)" ::: "memory");   // DMA(0) retired
    }
    __builtin_amdgcn_s_barrier();
    __builtin_amdgcn_sched_barrier(0);

    for (int kt = 0; kt < 64; ++kt) {
        int cur = kt & 1, nxt = cur ^ 1;
        int h_cur = kt % 3, h_nxt2 = (kt + 2) % 3;
        const bool more = (kt + 2 < 64);

        if (more) {                            // DMA(kt+2): ~2 phases to land
            const unsigned short* hp = hsrc + (kt + 2) * 64;
            async16(&hs[h_nxt2][w * 512], hp);
            async16(&hs[h_nxt2][4096 + w * 512], hp + 64 * 4096);
        }

        if (is_s) {
            if (kt + 1 < 64) {
                int ktn = (kt + 2 < 64) ? kt + 2 : 63;
                aGn = *(const bf16x8*)&gW[ktn * 2048];   // flies during s_tile
                s_tile(nxt);                             // S(kt+1) from aG
                aG = aGn;
            }
            __builtin_amdgcn_sched_barrier(0);
            if (more) asm volatile("s_waitcnt vmcnt(3) lgkmcnt(0)" ::: "memory");
            else      asm volatile("s_waitcnt vmcnt(1) lgkmcnt(0)" ::: "memory");
        } else {
            // ---- O += P(kt).H(kt) : 32x32x16, 4 key-steps, bH reused x2 ----
            const unsigned short* hcur = &hs[h_cur][0];
            const unsigned short* pcur = &pls[cur][0];
            __builtin_amdgcn_s_setprio(1);
#pragma unroll
            for (int ks = 0; ks < 4; ++ks) {
                int seg = (((2 * ks + hi) ^ (l31 & 7)) << 3);
                bf16x8 bH  = *(const bf16x8*)&hcur[(cb * 32 + l31) * 64 + seg];
                bf16x8 aP0 = *(const bf16x8*)&pcur[l31 * 64 + seg];
                bf16x8 aP1 = *(const bf16x8*)&pcur[(32 + l31) * 64 + seg];
                o0 = __builtin_amdgcn_mfma_f32_32x32x16_bf16(aP0, bH, o0, 0, 0, 0);
                o1 = __builtin_amdgcn_mfma_f32_32x32x16_bf16(aP1, bH, o1, 0, 0, 0);
            }
            __builtin_amdgcn_s_setprio(0);
            __builtin_amdgcn_sched_barrier(0);
            if (more) asm volatile("s_waitcnt vmcnt(2)" ::: "memory");
            else      asm volatile("s_waitcnt vmcnt(0)" ::: "memory");
        }

        __builtin_amdgcn_s_barrier();          // pls[nxt] + hs(kt+1) published
        __builtin_amdgcn_sched_barrier(0);
    }

    // ---- epilogue: l reduce (4 key-partials per row), O/l, residual ----
    if (is_s) {
#pragma unroll
        for (int nt = 0; nt < 4; ++nt) {
            float ps = lac[nt];
            ps += __shfl_xor(ps, 16);
            ps += __shfl_xor(ps, 32);
            if (q == 0) lpart[w][nt * 16 + n15] = ps;
        }
    }
    __syncthreads();
    if (t < 64) lrec[t] = 1.0f / (lpart[0][t] + lpart[1][t] + lpart[2][t] + lpart[3][t]);
    __syncthreads();
    if (!is_s) {
        float gam = *gamma_p;
        int ch = chbase + cb * 32 + l31;
#pragma unroll
        for (int qq = 0; qq < 4; ++qq) {
            int r0 = 8 * qq + 4 * hi;
            f32x4 ri0 = *(const f32x4*)&lrec[r0];
            f32x4 ri1 = *(const f32x4*)&lrec[32 + r0];
#pragma unroll
            for (int j = 0; j < 4; ++j) {
                int idx0 = (b * 4096 + qbase + r0 + j) * 256 + ch;
                int idx1 = idx0 + 32 * 256;
                out[idx0] = x[idx0] + gam * (o0[4 * qq + j] * ri0[j]);
                out[idx1] = x[idx1] + gam * (o1[4 * qq + j] * ri1[j]);
            }
        }
    }
}

// ---------------- launch ------------------------------------------------
extern "C" void kernel_launch(void* const* d_in, const int* in_sizes, int n_in,
                              void* d_out, int out_size, void* d_ws, size_t ws_size,
                              hipStream_t stream) {
    const float* x  = (const float*)d_in[0];
    const float* kf = (const float*)d_in[1];
    const float* kg = (const float*)d_in[2];
    const float* kh = (const float*)d_in[3];
    const float* gm = (const float*)d_in[4];
    float* out = (float*)d_out;

    char* ws = (char*)d_ws;
    unsigned short* wt = (unsigned short*)(ws);             // 320*256*2   = 163840 B
    unsigned short* fb = (unsigned short*)(ws + 163840);    // 16384*32*2  = 1 MiB
    unsigned short* gb = (unsigned short*)(ws + 1212416);   // 16384*32*2  = 1 MiB
    unsigned short* hT = (unsigned short*)(ws + 2260992);   // 4*256*4096*2= 8 MiB

    hipLaunchKernelGGL(k_wt,   dim3(320), dim3(256), 0, stream, kf, kg, kh, wt);
    hipLaunchKernelGGL(k_proj, dim3(256), dim3(512), 0, stream, x, wt, fb, gb, hT);
    hipLaunchKernelGGL(k_attn, dim3(512), dim3(512), 0, stream, x, fb, gb, hT, gm, out);
}